// Round 4
// baseline (13036.734 us; speedup 1.0000x reference)
//
#include <hip/hip_runtime.h>
#include <math.h>

constexpr int A_TOT  = 40001;
constexpr int NB     = 6;
constexpr int BN_TOT = 160001;
constexpr int AF     = 133;
constexpr int BF     = 147;
constexpr int H      = 300;
constexpr int NMOL   = 1000;
constexpr int ASZ    = 40;

#define FLAG_RELU 1
#define FLAG_ACC  2
#define FLAG_BIAS 4

// ===========================================================================
// K_A: msgA1[a,:] = relu(f_atoms[a]@Wi_atom) + sum_j(x_bj)*max_j(x_bj),
//      x_b = relu(f_bonds[b]@Wi_bond), b_j = a2b[a,j].  GA atoms per block.
// ===========================================================================
#define GA 8
__global__ __launch_bounds__(320) void k_msga1(
    const float* __restrict__ f_atoms, const float* __restrict__ f_bonds,
    const float* __restrict__ Wi_atom, const float* __restrict__ Wi_bond,
    const int* __restrict__ a2b, float* __restrict__ msgA1)
{
    __shared__ __align__(16) float fb[GA * NB][152];
    __shared__ __align__(16) float fa[GA][136];
    __shared__ int bidx[GA * NB];

    const int a0 = blockIdx.x * GA;
    const int tid = threadIdx.x;
    const int f = tid;

    if (tid < GA * NB) {
        int a = a0 + tid / NB;
        bidx[tid] = (a < A_TOT) ? a2b[a * NB + (tid % NB)] : 0;
    }
    __syncthreads();
    for (int idx = tid; idx < GA * NB * BF; idx += 320) {
        int i = idx / BF, k = idx - i * BF;
        fb[i][k] = f_bonds[(size_t)bidx[i] * BF + k];
    }
    for (int idx = tid; idx < GA * AF; idx += 320) {
        int l = idx / AF, k = idx - l * AF;
        int a = a0 + l;
        fa[l][k] = (a < A_TOT) ? f_atoms[(size_t)a * AF + k] : 0.f;
    }
    __syncthreads();

    if (f < H) {
        // ---- bond part: 48 dots of K=147
        float acc[GA * NB];
#pragma unroll
        for (int i = 0; i < GA * NB; ++i) acc[i] = 0.f;
        for (int k4 = 0; k4 < 144; k4 += 4) {
            float w0 = Wi_bond[(k4 + 0) * H + f];
            float w1 = Wi_bond[(k4 + 1) * H + f];
            float w2 = Wi_bond[(k4 + 2) * H + f];
            float w3 = Wi_bond[(k4 + 3) * H + f];
#pragma unroll
            for (int i = 0; i < GA * NB; ++i) {
                float4 b = *(const float4*)&fb[i][k4];
                acc[i] = fmaf(b.x, w0, fmaf(b.y, w1, fmaf(b.z, w2, fmaf(b.w, w3, acc[i]))));
            }
        }
        for (int k = 144; k < BF; ++k) {
            float wv = Wi_bond[k * H + f];
#pragma unroll
            for (int i = 0; i < GA * NB; ++i) acc[i] = fmaf(fb[i][k], wv, acc[i]);
        }
        float part[GA];
#pragma unroll
        for (int l = 0; l < GA; ++l) {
            float s = 0.f, mx = -INFINITY;
#pragma unroll
            for (int j = 0; j < NB; ++j) {
                float x = fmaxf(acc[l * NB + j], 0.f);
                s += x; mx = fmaxf(mx, x);
            }
            part[l] = s * mx;
        }
        // ---- atom part: 8 dots of K=133
        float acc2[GA];
#pragma unroll
        for (int l = 0; l < GA; ++l) acc2[l] = 0.f;
        for (int k4 = 0; k4 < 132; k4 += 4) {
            float w0 = Wi_atom[(k4 + 0) * H + f];
            float w1 = Wi_atom[(k4 + 1) * H + f];
            float w2 = Wi_atom[(k4 + 2) * H + f];
            float w3 = Wi_atom[(k4 + 3) * H + f];
#pragma unroll
            for (int l = 0; l < GA; ++l) {
                float4 b = *(const float4*)&fa[l][k4];
                acc2[l] = fmaf(b.x, w0, fmaf(b.y, w1, fmaf(b.z, w2, fmaf(b.w, w3, acc2[l]))));
            }
        }
        {
            float wv = Wi_atom[132 * H + f];
#pragma unroll
            for (int l = 0; l < GA; ++l) acc2[l] = fmaf(fa[l][132], wv, acc2[l]);
        }
#pragma unroll
        for (int l = 0; l < GA; ++l) {
            int a = a0 + l;
            if (a < A_TOT) msgA1[(size_t)a * H + f] = fmaxf(acc2[l], 0.f) + part[l];
        }
    }
}

// ===========================================================================
// K_B: msgA2[a,:] = msgA1[a,:] + sum_j(m1_rj)*max_j(m1_rj), r_j=a2b[a,j],
//   m1[r] = relu( x[r] + (msgA1[b2a[r]] - x[b2revb[r]]) @ Wh0 ),
//   x rows recomputed from f_bonds.  GB atoms (GB*6 rows) per block.
// ===========================================================================
#define GB 4
#define RB (GB * NB)   // 24
__global__ __launch_bounds__(320) void k_msga2(
    const float* __restrict__ f_bonds, const float* __restrict__ Wi_bond,
    const float* __restrict__ Wh0,
    const float* __restrict__ msgA1, float* __restrict__ msgA2,
    const int* __restrict__ a2b, const int* __restrict__ b2a,
    const int* __restrict__ b2revb)
{
    __shared__ __align__(16) float v[RB][304];
    __shared__ __align__(16) float fbl[RB][152];
    __shared__ int r_[RB], q_[RB], p_[RB];

    const int a0 = blockIdx.x * GB;
    const int tid = threadIdx.x;
    const int f = tid;

    if (tid < RB) {
        int a = a0 + tid / NB;
        int r = (a < A_TOT) ? a2b[a * NB + (tid % NB)] : 0;
        r_[tid] = r;
        q_[tid] = b2revb[r];
        p_[tid] = b2a[r];
    }
    __syncthreads();
    // v <- msgA1[p_i];  fbl <- f_bonds[q_i]
    for (int idx = tid; idx < RB * H; idx += 320) {
        int i = idx / H, k = idx - i * H;
        v[i][k] = msgA1[(size_t)p_[i] * H + k];
    }
    for (int idx = tid; idx < RB * BF; idx += 320) {
        int i = idx / BF, k = idx - i * BF;
        fbl[i][k] = f_bonds[(size_t)q_[i] * BF + k];
    }
    __syncthreads();
    // v[i][f] -= relu(xq_i[f])
    if (f < H) {
        float acc[RB];
#pragma unroll
        for (int i = 0; i < RB; ++i) acc[i] = 0.f;
        for (int k4 = 0; k4 < 144; k4 += 4) {
            float w0 = Wi_bond[(k4 + 0) * H + f];
            float w1 = Wi_bond[(k4 + 1) * H + f];
            float w2 = Wi_bond[(k4 + 2) * H + f];
            float w3 = Wi_bond[(k4 + 3) * H + f];
#pragma unroll
            for (int i = 0; i < RB; ++i) {
                float4 b = *(const float4*)&fbl[i][k4];
                acc[i] = fmaf(b.x, w0, fmaf(b.y, w1, fmaf(b.z, w2, fmaf(b.w, w3, acc[i]))));
            }
        }
        for (int k = 144; k < BF; ++k) {
            float wv = Wi_bond[k * H + f];
#pragma unroll
            for (int i = 0; i < RB; ++i) acc[i] = fmaf(fbl[i][k], wv, acc[i]);
        }
#pragma unroll
        for (int i = 0; i < RB; ++i) v[i][f] -= fmaxf(acc[i], 0.f);
    }
    __syncthreads();
    // fbl <- f_bonds[r_i]
    for (int idx = tid; idx < RB * BF; idx += 320) {
        int i = idx / BF, k = idx - i * BF;
        fbl[i][k] = f_bonds[(size_t)r_[i] * BF + k];
    }
    __syncthreads();
    if (f < H) {
        // GEMV: accm_i = v_i @ Wh0[:, f]   (K=300)
        float accm[RB];
#pragma unroll
        for (int i = 0; i < RB; ++i) accm[i] = 0.f;
        for (int k4 = 0; k4 < H; k4 += 4) {
            float w0 = Wh0[(k4 + 0) * H + f];
            float w1 = Wh0[(k4 + 1) * H + f];
            float w2 = Wh0[(k4 + 2) * H + f];
            float w3 = Wh0[(k4 + 3) * H + f];
#pragma unroll
            for (int i = 0; i < RB; ++i) {
                float4 b = *(const float4*)&v[i][k4];
                accm[i] = fmaf(b.x, w0, fmaf(b.y, w1, fmaf(b.z, w2, fmaf(b.w, w3, accm[i]))));
            }
        }
        // xr_i[f]
        float accr[RB];
#pragma unroll
        for (int i = 0; i < RB; ++i) accr[i] = 0.f;
        for (int k4 = 0; k4 < 144; k4 += 4) {
            float w0 = Wi_bond[(k4 + 0) * H + f];
            float w1 = Wi_bond[(k4 + 1) * H + f];
            float w2 = Wi_bond[(k4 + 2) * H + f];
            float w3 = Wi_bond[(k4 + 3) * H + f];
#pragma unroll
            for (int i = 0; i < RB; ++i) {
                float4 b = *(const float4*)&fbl[i][k4];
                accr[i] = fmaf(b.x, w0, fmaf(b.y, w1, fmaf(b.z, w2, fmaf(b.w, w3, accr[i]))));
            }
        }
        for (int k = 144; k < BF; ++k) {
            float wv = Wi_bond[k * H + f];
#pragma unroll
            for (int i = 0; i < RB; ++i) accr[i] = fmaf(fbl[i][k], wv, accr[i]);
        }
#pragma unroll
        for (int l = 0; l < GB; ++l) {
            float s = 0.f, mx = -INFINITY;
#pragma unroll
            for (int j = 0; j < NB; ++j) {
                int i = l * NB + j;
                float m1 = fmaxf(fmaxf(accr[i], 0.f) + accm[i], 0.f);
                s += m1; mx = fmaxf(mx, m1);
            }
            int a = a0 + l;
            if (a < A_TOT)
                msgA2[(size_t)a * H + f] = msgA1[(size_t)a * H + f] + s * mx;
        }
    }
}

// ===========================================================================
// K_C: fused agg3 + W_lr.  Per atom a:
//   m2[b] = relu( x[b] + (msgA2[b2a[b]] - m1[b2revb[b]]) @ Wh1 ),  b=a2b[a,j]
//   m1[r'] recomputed as in K_B.  agg3 = sum_j(m2)*max_j(m2).
//   aggL[a] = agg3@W_lr[0:300] + msgA2[a]@W_lr[300:600]
//           + relu(f_atoms[a]@Wi_atom)@W_lr[600:900]
// GC atoms (GC*6 rows) per block.
// ===========================================================================
#define GC 2
#define RC (GC * NB)   // 12
__global__ __launch_bounds__(320) void k_aggl(
    const float* __restrict__ f_atoms, const float* __restrict__ f_bonds,
    const float* __restrict__ Wi_atom, const float* __restrict__ Wi_bond,
    const float* __restrict__ Wh0, const float* __restrict__ Wh1,
    const float* __restrict__ W_lr,
    const float* __restrict__ msgA1, const float* __restrict__ msgA2,
    const int* __restrict__ a2b, const int* __restrict__ b2a,
    const int* __restrict__ b2revb, float* __restrict__ aggL)
{
    __shared__ __align__(16) float u[RC][304];     // m1-recompute operand
    __shared__ __align__(16) float w[RC][304];     // m2 GEMV operand
    __shared__ __align__(16) float fbl[RC][152];
    __shared__ __align__(16) float agg3r[GC][304];
    __shared__ __align__(16) float mA2r[GC][304];
    __shared__ __align__(16) float inAr[GC][304];
    __shared__ __align__(16) float fa[GC][136];
    __shared__ int b_[RC], rp_[RC], p1_[RC], q1_[RC], p2_[RC];

    const int a0 = blockIdx.x * GC;
    const int tid = threadIdx.x;
    const int f = tid;

    if (tid < RC) {
        int a = a0 + tid / NB;
        int b = (a < A_TOT) ? a2b[a * NB + (tid % NB)] : 0;
        int rp = b2revb[b];
        b_[tid] = b; rp_[tid] = rp;
        p1_[tid] = b2a[rp]; q1_[tid] = b2revb[rp]; p2_[tid] = b2a[b];
    }
    __syncthreads();
    for (int idx = tid; idx < RC * H; idx += 320) {
        int i = idx / H, k = idx - i * H;
        u[i][k] = msgA1[(size_t)p1_[i] * H + k];
        w[i][k] = msgA2[(size_t)p2_[i] * H + k];
    }
    for (int idx = tid; idx < RC * BF; idx += 320) {
        int i = idx / BF, k = idx - i * BF;
        fbl[i][k] = f_bonds[(size_t)q1_[i] * BF + k];
    }
    for (int idx = tid; idx < GC * H; idx += 320) {
        int l = idx / H, k = idx - l * H;
        int a = a0 + l;
        mA2r[l][k] = (a < A_TOT) ? msgA2[(size_t)a * H + k] : 0.f;
    }
    for (int idx = tid; idx < GC * AF; idx += 320) {
        int l = idx / AF, k = idx - l * AF;
        int a = a0 + l;
        fa[l][k] = (a < A_TOT) ? f_atoms[(size_t)a * AF + k] : 0.f;
    }
    __syncthreads();
    // u[i][f] -= relu(xq'_i[f])
    if (f < H) {
        float acc[RC];
#pragma unroll
        for (int i = 0; i < RC; ++i) acc[i] = 0.f;
        for (int k4 = 0; k4 < 144; k4 += 4) {
            float w0 = Wi_bond[(k4 + 0) * H + f];
            float w1 = Wi_bond[(k4 + 1) * H + f];
            float w2 = Wi_bond[(k4 + 2) * H + f];
            float w3 = Wi_bond[(k4 + 3) * H + f];
#pragma unroll
            for (int i = 0; i < RC; ++i) {
                float4 b = *(const float4*)&fbl[i][k4];
                acc[i] = fmaf(b.x, w0, fmaf(b.y, w1, fmaf(b.z, w2, fmaf(b.w, w3, acc[i]))));
            }
        }
        for (int k = 144; k < BF; ++k) {
            float wv = Wi_bond[k * H + f];
#pragma unroll
            for (int i = 0; i < RC; ++i) acc[i] = fmaf(fbl[i][k], wv, acc[i]);
        }
#pragma unroll
        for (int i = 0; i < RC; ++i) u[i][f] -= fmaxf(acc[i], 0.f);
    }
    __syncthreads();
    // fbl <- f_bonds[rp_i]
    for (int idx = tid; idx < RC * BF; idx += 320) {
        int i = idx / BF, k = idx - i * BF;
        fbl[i][k] = f_bonds[(size_t)rp_[i] * BF + k];
    }
    __syncthreads();
    // m1_i[f] = relu(relu(xr'_i[f]) + u_i@Wh0[:,f]);  w[i][f] -= m1_i[f]
    if (f < H) {
        float accm[RC];
#pragma unroll
        for (int i = 0; i < RC; ++i) accm[i] = 0.f;
        for (int k4 = 0; k4 < H; k4 += 4) {
            float w0 = Wh0[(k4 + 0) * H + f];
            float w1 = Wh0[(k4 + 1) * H + f];
            float w2 = Wh0[(k4 + 2) * H + f];
            float w3 = Wh0[(k4 + 3) * H + f];
#pragma unroll
            for (int i = 0; i < RC; ++i) {
                float4 b = *(const float4*)&u[i][k4];
                accm[i] = fmaf(b.x, w0, fmaf(b.y, w1, fmaf(b.z, w2, fmaf(b.w, w3, accm[i]))));
            }
        }
        float accr[RC];
#pragma unroll
        for (int i = 0; i < RC; ++i) accr[i] = 0.f;
        for (int k4 = 0; k4 < 144; k4 += 4) {
            float w0 = Wi_bond[(k4 + 0) * H + f];
            float w1 = Wi_bond[(k4 + 1) * H + f];
            float w2 = Wi_bond[(k4 + 2) * H + f];
            float w3 = Wi_bond[(k4 + 3) * H + f];
#pragma unroll
            for (int i = 0; i < RC; ++i) {
                float4 b = *(const float4*)&fbl[i][k4];
                accr[i] = fmaf(b.x, w0, fmaf(b.y, w1, fmaf(b.z, w2, fmaf(b.w, w3, accr[i]))));
            }
        }
        for (int k = 144; k < BF; ++k) {
            float wv = Wi_bond[k * H + f];
#pragma unroll
            for (int i = 0; i < RC; ++i) accr[i] = fmaf(fbl[i][k], wv, accr[i]);
        }
#pragma unroll
        for (int i = 0; i < RC; ++i)
            w[i][f] -= fmaxf(fmaxf(accr[i], 0.f) + accm[i], 0.f);
    }
    __syncthreads();
    // fbl <- f_bonds[b_i]
    for (int idx = tid; idx < RC * BF; idx += 320) {
        int i = idx / BF, k = idx - i * BF;
        fbl[i][k] = f_bonds[(size_t)b_[i] * BF + k];
    }
    __syncthreads();
    // m2_i[f] = relu(relu(xb_i[f]) + w_i@Wh1[:,f]); agg3; inA
    if (f < H) {
        float accm[RC];
#pragma unroll
        for (int i = 0; i < RC; ++i) accm[i] = 0.f;
        for (int k4 = 0; k4 < H; k4 += 4) {
            float w0 = Wh1[(k4 + 0) * H + f];
            float w1 = Wh1[(k4 + 1) * H + f];
            float w2 = Wh1[(k4 + 2) * H + f];
            float w3 = Wh1[(k4 + 3) * H + f];
#pragma unroll
            for (int i = 0; i < RC; ++i) {
                float4 b = *(const float4*)&w[i][k4];
                accm[i] = fmaf(b.x, w0, fmaf(b.y, w1, fmaf(b.z, w2, fmaf(b.w, w3, accm[i]))));
            }
        }
        float accb[RC];
#pragma unroll
        for (int i = 0; i < RC; ++i) accb[i] = 0.f;
        for (int k4 = 0; k4 < 144; k4 += 4) {
            float w0 = Wi_bond[(k4 + 0) * H + f];
            float w1 = Wi_bond[(k4 + 1) * H + f];
            float w2 = Wi_bond[(k4 + 2) * H + f];
            float w3 = Wi_bond[(k4 + 3) * H + f];
#pragma unroll
            for (int i = 0; i < RC; ++i) {
                float4 b = *(const float4*)&fbl[i][k4];
                accb[i] = fmaf(b.x, w0, fmaf(b.y, w1, fmaf(b.z, w2, fmaf(b.w, w3, accb[i]))));
            }
        }
        for (int k = 144; k < BF; ++k) {
            float wv = Wi_bond[k * H + f];
#pragma unroll
            for (int i = 0; i < RC; ++i) accb[i] = fmaf(fbl[i][k], wv, accb[i]);
        }
#pragma unroll
        for (int l = 0; l < GC; ++l) {
            float s = 0.f, mx = -INFINITY;
#pragma unroll
            for (int j = 0; j < NB; ++j) {
                int i = l * NB + j;
                float m2 = fmaxf(fmaxf(accb[i], 0.f) + accm[i], 0.f);
                s += m2; mx = fmaxf(mx, m2);
            }
            agg3r[l][f] = s * mx;
        }
        // inA rows
        float acc2[GC];
#pragma unroll
        for (int l = 0; l < GC; ++l) acc2[l] = 0.f;
        for (int k4 = 0; k4 < 132; k4 += 4) {
            float w0 = Wi_atom[(k4 + 0) * H + f];
            float w1 = Wi_atom[(k4 + 1) * H + f];
            float w2 = Wi_atom[(k4 + 2) * H + f];
            float w3 = Wi_atom[(k4 + 3) * H + f];
#pragma unroll
            for (int l = 0; l < GC; ++l) {
                float4 b = *(const float4*)&fa[l][k4];
                acc2[l] = fmaf(b.x, w0, fmaf(b.y, w1, fmaf(b.z, w2, fmaf(b.w, w3, acc2[l]))));
            }
        }
        {
            float wv = Wi_atom[132 * H + f];
#pragma unroll
            for (int l = 0; l < GC; ++l) acc2[l] = fmaf(fa[l][132], wv, acc2[l]);
        }
#pragma unroll
        for (int l = 0; l < GC; ++l) inAr[l][f] = fmaxf(acc2[l], 0.f);
    }
    __syncthreads();
    // aggL[a] = agg3r@Wlr1 + mA2r@Wlr2 + inAr@Wlr3
    if (f < H) {
        float accL[GC];
#pragma unroll
        for (int l = 0; l < GC; ++l) accL[l] = 0.f;
        for (int k4 = 0; k4 < H; k4 += 4) {
#pragma unroll
            for (int kk = 0; kk < 4; ++kk) {
                int k = k4 + kk;
                float w1v = W_lr[(size_t)k * H + f];
                float w2v = W_lr[(size_t)(H + k) * H + f];
                float w3v = W_lr[(size_t)(2 * H + k) * H + f];
#pragma unroll
                for (int l = 0; l < GC; ++l) {
                    accL[l] = fmaf(agg3r[l][k], w1v,
                              fmaf(mA2r[l][k], w2v,
                              fmaf(inAr[l][k], w3v, accL[l])));
                }
            }
        }
#pragma unroll
        for (int l = 0; l < GC; ++l) {
            int a = a0 + l;
            if (a < A_TOT) aggL[(size_t)a * H + f] = accL[l];
        }
    }
}

// ===========================================================================
// Transpose 4 [900,300] fp32 weight mats -> [300,900]
// ===========================================================================
__global__ __launch_bounds__(256) void transpose4_kernel(
    const float* __restrict__ s0, const float* __restrict__ s1,
    const float* __restrict__ s2, const float* __restrict__ s3,
    float* __restrict__ d0, float* __restrict__ d1,
    float* __restrict__ d2, float* __restrict__ d3)
{
    const float* S[4] = {s0, s1, s2, s3};
    float* D[4] = {d0, d1, d2, d3};
    int z = blockIdx.y;
    int idx = blockIdx.x * 256 + threadIdx.x;
    if (idx < 900 * 300) {
        int k = idx / 900;
        int g = idx - k * 900;
        D[z][idx] = S[z][g * 300 + k];
    }
}

// ===========================================================================
// prep: h0[m] = max_t aggL[1+m*40+t]; then aggL row <- relu(row + gru_bias)
// (in-place; message view = aggL + H)
// ===========================================================================
__global__ __launch_bounds__(256) void prep_kernel(
    float* aggL, const float* __restrict__ gru_bias, float* __restrict__ h0)
{
    int m = blockIdx.x;
    for (int f = threadIdx.x; f < H; f += 256) {
        float b = gru_bias[f];
        float mx = -INFINITY;
        for (int t = 0; t < ASZ; ++t) {
            size_t o = (size_t)(1 + m * ASZ + t) * H + f;
            float v = aggL[o];
            mx = fmaxf(mx, v);
            aggL[o] = fmaxf(v + b, 0.f);
        }
        h0[(size_t)m * H + f] = mx;
    }
}

__device__ __forceinline__ float dev_sigmoid(float x) {
    return 1.f / (1.f + __expf(-x));
}
__device__ __forceinline__ float dev_tanh(float x) {
    return 1.f - 2.f / (__expf(2.f * x) + 1.f);
}

// ===========================================================================
// GRU step (both dirs via blockIdx.z).  xp recomputed from message rows.
// Block (64,4): 64 feats x 4 mol-slots; 16 mols & 64 feats per block.
// WTih/WThh are [300][900] (g-major within row: [r|z|n]).
// ===========================================================================
__global__ __launch_bounds__(256) void k_gru_step(
    int s, const float* __restrict__ msg,   // [40000,300] (= aggL + H)
    const float* __restrict__ WTih_f, const float* __restrict__ WThh_f,
    const float* __restrict__ bih_f, const float* __restrict__ bhh_f,
    const float* __restrict__ WTih_b, const float* __restrict__ WThh_b,
    const float* __restrict__ bih_b, const float* __restrict__ bhh_b,
    const float* __restrict__ h0, float* out_f, float* out_b)
{
    __shared__ __align__(16) float hs[16][304];
    __shared__ __align__(16) float ms[16][304];

    const int dir = blockIdx.z;
    const float* WTih = dir ? WTih_b : WTih_f;
    const float* WThh = dir ? WThh_b : WThh_f;
    const float* bih  = dir ? bih_b : bih_f;
    const float* bhh  = dir ? bhh_b : bhh_f;
    float* out        = dir ? out_b : out_f;

    const int t     = dir ? (ASZ - 1 - s) : s;
    const int tprev = dir ? (t + 1) : (t - 1);

    const int m0 = blockIdx.x * 16;
    const int f0 = blockIdx.y * 64;
    const int tx = threadIdx.x;
    const int ty = threadIdx.y;
    const int tid = ty * 64 + tx;

    for (int idx = tid; idx < 16 * H; idx += 256) {
        int ml = idx / H, k = idx - ml * H;
        int m = m0 + ml;
        float hv = 0.f, mv = 0.f;
        if (m < NMOL) {
            hv = (s == 0) ? h0[(size_t)m * H + k]
                          : out[(size_t)(m * ASZ + tprev) * H + k];
            mv = msg[(size_t)(m * ASZ + t) * H + k];
        }
        hs[ml][k] = hv;
        ms[ml][k] = mv;
    }
    __syncthreads();

    const int f = f0 + tx;
    const int fc = (f < H) ? f : 0;

    float aR[4] = {0,0,0,0}, aZ[4] = {0,0,0,0};
    float aIN[4] = {0,0,0,0}, aHN[4] = {0,0,0,0};

    for (int k4 = 0; k4 < H; k4 += 4) {
#pragma unroll
        for (int kk = 0; kk < 4; ++kk) {
            int k = k4 + kk;
            const float* wi = WTih + (size_t)k * 900;
            const float* wh = WThh + (size_t)k * 900;
            float wir = wi[fc], wiz = wi[300 + fc], win = wi[600 + fc];
            float whr = wh[fc], whz = wh[300 + fc], whn = wh[600 + fc];
#pragma unroll
            for (int i = 0; i < 4; ++i) {
                float mv = ms[ty + 4 * i][k];
                float hv = hs[ty + 4 * i][k];
                aR[i]  = fmaf(mv, wir, fmaf(hv, whr, aR[i]));
                aZ[i]  = fmaf(mv, wiz, fmaf(hv, whz, aZ[i]));
                aIN[i] = fmaf(mv, win, aIN[i]);
                aHN[i] = fmaf(hv, whn, aHN[i]);
            }
        }
    }

    if (f < H) {
        float bir = bih[f], biz = bih[300 + f], bin = bih[600 + f];
        float bhr = bhh[f], bhz = bhh[300 + f], bhn = bhh[600 + f];
#pragma unroll
        for (int i = 0; i < 4; ++i) {
            int m = m0 + ty + 4 * i;
            if (m >= NMOL) continue;
            float r = dev_sigmoid(aR[i] + bir + bhr);
            float z = dev_sigmoid(aZ[i] + biz + bhz);
            float n = dev_tanh(aIN[i] + bin + r * (aHN[i] + bhn));
            float hprev = hs[ty + 4 * i][f];
            out[(size_t)(m * ASZ + t) * H + f] = (1.f - z) * n + z * hprev;
        }
    }
}

// ===========================================================================
// Tiled fp32 GEMM (for W_o): C = epi(A@W), W row-major [K,N].
// ===========================================================================
__global__ __launch_bounds__(256) void gemm_kernel(
    const float* __restrict__ A, const float* __restrict__ W,
    float* C, int M, int K, int N,
    const float* __restrict__ bias, int flags)
{
    __shared__ float As[16][64];
    __shared__ float Bs[16][64];
    const int tx = threadIdx.x, ty = threadIdx.y;
    const int tid = ty * 16 + tx;
    const int m0 = blockIdx.x * 64, n0 = blockIdx.y * 64;
    const int am = tid >> 2, ak = (tid & 3) * 4;
    const int bk = tid >> 4, bn = (tid & 15) * 4;
    const int arow = m0 + am;

    float acc[4][4];
#pragma unroll
    for (int i = 0; i < 4; ++i)
#pragma unroll
        for (int j = 0; j < 4; ++j) acc[i][j] = 0.f;

    for (int k0 = 0; k0 < K; k0 += 16) {
#pragma unroll
        for (int j = 0; j < 4; ++j) {
            int k = k0 + ak + j;
            As[ak + j][am] = (arow < M && k < K) ? A[(size_t)arow * K + k] : 0.f;
        }
#pragma unroll
        for (int j = 0; j < 4; ++j) {
            int k = k0 + bk, n = n0 + bn + j;
            Bs[bk][bn + j] = (k < K && n < N) ? W[(size_t)k * N + n] : 0.f;
        }
        __syncthreads();
#pragma unroll
        for (int kk = 0; kk < 16; ++kk) {
            float4 av = *(const float4*)&As[kk][ty * 4];
            float4 bv = *(const float4*)&Bs[kk][tx * 4];
            float a4[4] = {av.x, av.y, av.z, av.w};
            float b4[4] = {bv.x, bv.y, bv.z, bv.w};
#pragma unroll
            for (int i = 0; i < 4; ++i)
#pragma unroll
                for (int j = 0; j < 4; ++j)
                    acc[i][j] = fmaf(a4[i], b4[j], acc[i][j]);
        }
        __syncthreads();
    }
#pragma unroll
    for (int i = 0; i < 4; ++i) {
        int m = m0 + ty * 4 + i;
        if (m >= M) continue;
#pragma unroll
        for (int j = 0; j < 4; ++j) {
            int n = n0 + tx * 4 + j;
            if (n >= N) continue;
            float v = acc[i][j];
            if (flags & FLAG_BIAS) v += bias[n];
            if (flags & FLAG_ACC)  v += C[(size_t)m * N + n];
            if (flags & FLAG_RELU) v = fmaxf(v, 0.f);
            C[(size_t)m * N + n] = v;
        }
    }
}

__global__ __launch_bounds__(256) void mean_kernel(
    const float* __restrict__ hid, float* __restrict__ out)
{
    int m = blockIdx.x;
    for (int f = threadIdx.x; f < H; f += 256) {
        float s = 0.f;
        for (int t = 0; t < ASZ; ++t)
            s += hid[(size_t)(m * ASZ + t) * H + f];
        out[(size_t)m * H + f] = s * (1.f / 40.f);
    }
}

// ===========================================================================
extern "C" void kernel_launch(void* const* d_in, const int* in_sizes, int n_in,
                              void* d_out, int out_size, void* d_ws, size_t ws_size,
                              hipStream_t stream)
{
    const float* f_atoms  = (const float*)d_in[0];
    const float* f_bonds  = (const float*)d_in[1];
    const float* Wi_atom  = (const float*)d_in[2];
    const float* Wi_bond  = (const float*)d_in[3];
    const float* Wh0      = (const float*)d_in[4];
    const float* Wh1      = (const float*)d_in[5];
    const float* W_lr     = (const float*)d_in[6];
    const float* W_o      = (const float*)d_in[7];
    const float* b_o      = (const float*)d_in[8];
    const float* gru_bias = (const float*)d_in[9];
    const float* gWih_f   = (const float*)d_in[10];
    const float* gWhh_f   = (const float*)d_in[11];
    const float* gbih_f   = (const float*)d_in[12];
    const float* gbhh_f   = (const float*)d_in[13];
    const float* gWih_b   = (const float*)d_in[14];
    const float* gWhh_b   = (const float*)d_in[15];
    const float* gbih_b   = (const float*)d_in[16];
    const float* gbhh_b   = (const float*)d_in[17];
    const int*   a2b      = (const int*)d_in[18];
    const int*   b2a      = (const int*)d_in[19];
    const int*   b2revb   = (const int*)d_in[20];

    // Workspace (fp32 floats). Peak = 60,000,900 floats = 240,003,600 B.
    //  [0,12000300)           msgA1   (dead after k_aggl; then h0@0, WT@300000)
    //  [12000300,24000600)    msgA2   (dead after k_aggl; then hid)
    //  [24000600,36000900)    aggL -> message (in-place)
    //  [36000900,48000900)    outf
    //  [48000900,60000900)    outb
    float* ws = (float*)d_ws;
    float* msgA1 = ws;
    float* msgA2 = ws + 12000300;
    float* aggL  = ws + 24000600;
    float* outf  = ws + 36000900;
    float* outb  = ws + 48000900;
    float* h0    = ws;            // overlay (post k_aggl)
    float* WTihf = ws + 300000;
    float* WThhf = ws + 570000;
    float* WTihb = ws + 840000;
    float* WThhb = ws + 1110000;
    float* hid   = msgA2;         // overlay (post k_aggl)
    float* msg   = aggL + H;      // rows 1..40000 view

    // 1. msgA1
    k_msga1<<<(A_TOT + GA - 1) / GA, 320, 0, stream>>>(
        f_atoms, f_bonds, Wi_atom, Wi_bond, a2b, msgA1);

    // 2. msgA2
    k_msga2<<<(A_TOT + GB - 1) / GB, 320, 0, stream>>>(
        f_bonds, Wi_bond, Wh0, msgA1, msgA2, a2b, b2a, b2revb);

    // 3. fused agg3 + W_lr -> aggL
    k_aggl<<<(A_TOT + GC - 1) / GC, 320, 0, stream>>>(
        f_atoms, f_bonds, Wi_atom, Wi_bond, Wh0, Wh1, W_lr,
        msgA1, msgA2, a2b, b2a, b2revb, aggL);

    // 4. transpose GRU weights (into dead msgA1 region)
    {
        dim3 g((270000 + 255) / 256, 4);
        transpose4_kernel<<<g, 256, 0, stream>>>(gWih_f, gWhh_f, gWih_b, gWhh_b,
                                                 WTihf, WThhf, WTihb, WThhb);
    }

    // 5. h0 + in-place relu(aggL + bias)
    prep_kernel<<<NMOL, 256, 0, stream>>>(aggL, gru_bias, h0);

    // 6. GRU recurrence, xp recomputed per step
    {
        dim3 grid((NMOL + 15) / 16, (H + 63) / 64, 2);
        dim3 block(64, 4);
        for (int s = 0; s < ASZ; ++s) {
            k_gru_step<<<grid, block, 0, stream>>>(
                s, msg, WTihf, WThhf, gbih_f, gbhh_f,
                WTihb, WThhb, gbih_b, gbhh_b, h0, outf, outb);
        }
    }

    // 7. hid = relu(outf@W_o[:300] + outb@W_o[300:] + b_o)
    {
        dim3 grid((NMOL * ASZ + 63) / 64, (H + 63) / 64);
        dim3 block(16, 16);
        gemm_kernel<<<grid, block, 0, stream>>>(outf, W_o, hid,
            NMOL * ASZ, H, H, nullptr, 0);
        gemm_kernel<<<grid, block, 0, stream>>>(outb, W_o + 300 * 300, hid,
            NMOL * ASZ, H, H, b_o, FLAG_ACC | FLAG_BIAS | FLAG_RELU);
    }

    // 8. per-mol mean -> d_out
    mean_kernel<<<NMOL, 256, 0, stream>>>(hid, (float*)d_out);
}